// Round 4
// baseline (584.675 us; speedup 1.0000x reference)
//
#include <hip/hip_runtime.h>
#include <math.h>

#define CIN  32
#define COUT 64
#define KVOL 27
#define EPSF 1e-5f

typedef __attribute__((ext_vector_type(8))) short          short8;
typedef __attribute__((ext_vector_type(8))) unsigned short u16x8;
typedef __attribute__((ext_vector_type(4))) float          float4v;

__device__ __forceinline__ float eluf(float x) { return x > 0.f ? x : expm1f(x); }

// f32 -> bf16 round-to-nearest-even
__device__ __forceinline__ unsigned short f2bf(float x) {
    unsigned u = __float_as_uint(x);
    unsigned r = (u + 0x7FFFu + ((u >> 16) & 1u)) >> 16;
    return (unsigned short)r;
}
__device__ __forceinline__ unsigned pk2bf(float lo, float hi) {
    return (unsigned)f2bf(lo) | ((unsigned)f2bf(hi) << 16);
}
__device__ __forceinline__ float bf2f(unsigned short h) {
    return __uint_as_float(((unsigned)h) << 16);
}

// ---------------------------------------------------------------------------
// prep: fused cvt_w (blocks 0..54) + bucket build (next nbB blocks) +
// nbr-map inversion (next nbL*KVOL blocks). All three are independent.
// ---------------------------------------------------------------------------
__global__ void prep_kernel(const float* __restrict__ W1, const float* __restrict__ W2,
                            const float* __restrict__ Wd,
                            unsigned short* __restrict__ Wt1, unsigned short* __restrict__ Wt2,
                            unsigned short* __restrict__ Wdt,
                            const int* __restrict__ pool_seg, int* __restrict__ cnt,
                            int* __restrict__ bucket, int N,
                            const int* __restrict__ conv_out, const int* __restrict__ conv_in,
                            int* __restrict__ nbrT, int L, int M, int nbB, int nbL)
{
    int b = blockIdx.x, t = threadIdx.x;
    if (b < 55) {
        if (b == 54) {
            for (int e = t; e < CIN * COUT; e += 256) {
                int i = e >> 6, c = e & 63;
                Wdt[c * CIN + i] = f2bf(Wd[e]);
            }
            return;
        }
        const float* W = (b < 27) ? W1 : W2;
        unsigned short* Wt = (b < 27) ? Wt1 : Wt2;
        int k = (b < 27) ? b : b - 27;
        const float* src = W + (size_t)k * (COUT * COUT);
        unsigned short* dst = Wt + (size_t)k * (COUT * COUT);
        for (int e = t; e < COUT * COUT; e += 256) {
            int i = e >> 6, c = e & 63;
            dst[c * COUT + i] = f2bf(src[e]);
        }
        return;
    }
    b -= 55;
    if (b < nbB) {  // bucket: pooling cell = 2x2x4 -> capacity 16
        int j = b * 256 + t;
        if (j < N) {
            int s = pool_seg[j];
            int pos = atomicAdd(&cnt[s], 1);
            bucket[(size_t)s * 16 + pos] = j;
        }
        return;
    }
    b -= nbB;  // nbr: invert (k, pairlist) into nbrT[k][M]
    int k = b / nbL, blk = b - k * nbL;
    int idx = blk * 256 + t;
    if (idx < L) {
        int e = k * L + idx;
        int j = conv_out[e];
        if (j < M) nbrT[(size_t)k * M + j] = conv_in[e];
    }
}

// ---------------------------------------------------------------------------
// Transposed streaming down-conv: t^T = Wd^T @ feats^T, zero LDS in hot loop.
// ---------------------------------------------------------------------------
__global__ __launch_bounds__(256) void gemm_t_kernel(
    const float* __restrict__ feats, const unsigned short* __restrict__ Wdt,
    int N, unsigned short* __restrict__ t_bf, float* __restrict__ red0)
{
    __shared__ float red_s[64];
    __shared__ float red_q[64];
    int t = threadIdx.x;
    if (t < 64) { red_s[t] = 0.f; red_q[t] = 0.f; }
    __syncthreads();

    int w = t >> 6, lane = t & 63, l15 = lane & 15, quad = lane >> 4;

    short8 aw[4];
    #pragma unroll
    for (int mt = 0; mt < 4; ++mt)
        aw[mt] = *(const short8*)(Wdt + (size_t)(16 * mt + l15) * CIN + quad * 8);

    float s1[16], sq[16];
    #pragma unroll
    for (int e = 0; e < 16; ++e) { s1[e] = 0.f; sq[e] = 0.f; }

    int numTiles = (N + 15) >> 4;
    int stride = gridDim.x * 4;
    int tile = blockIdx.x * 4 + w;

    float4 c0 = make_float4(0.f, 0.f, 0.f, 0.f), c1 = c0;
    {
        int pt = tile * 16 + l15;
        if (tile < numTiles && pt < N) {
            const float4* s = (const float4*)(feats + (size_t)pt * CIN + quad * 8);
            c0 = s[0]; c1 = s[1];
        }
    }

    while (tile < numTiles) {
        int nt = tile + stride;
        float4 n0 = make_float4(0.f, 0.f, 0.f, 0.f), n1 = n0;
        {
            int npt = nt * 16 + l15;
            if (nt < numTiles && npt < N) {
                const float4* s = (const float4*)(feats + (size_t)npt * CIN + quad * 8);
                n0 = s[0]; n1 = s[1];
            }
        }
        union { short8 v; unsigned u[4]; } b;
        b.u[0] = pk2bf(c0.x, c0.y);
        b.u[1] = pk2bf(c0.z, c0.w);
        b.u[2] = pk2bf(c1.x, c1.y);
        b.u[3] = pk2bf(c1.z, c1.w);

        float4v acc[4];
        #pragma unroll
        for (int mt = 0; mt < 4; ++mt)
            acc[mt] = __builtin_amdgcn_mfma_f32_16x16x32_bf16(
                aw[mt], b.v, (float4v){0.f, 0.f, 0.f, 0.f}, 0, 0, 0);

        int pt = tile * 16 + l15;
        if (pt < N) {
            #pragma unroll
            for (int mt = 0; mt < 4; ++mt) {
                uint2 o;
                o.x = pk2bf(acc[mt][0], acc[mt][1]);
                o.y = pk2bf(acc[mt][2], acc[mt][3]);
                *(uint2*)(t_bf + (size_t)pt * COUT + mt * 16 + quad * 4) = o;
            }
        }
        #pragma unroll
        for (int mt = 0; mt < 4; ++mt)
            #pragma unroll
            for (int e = 0; e < 4; ++e) {
                float v = acc[mt][e];
                s1[mt * 4 + e] += v; sq[mt * 4 + e] += v * v;
            }
        c0 = n0; c1 = n1;
        tile = nt;
    }

    #pragma unroll
    for (int m = 1; m <= 8; m <<= 1) {
        #pragma unroll
        for (int e = 0; e < 16; ++e) {
            s1[e] += __shfl_xor(s1[e], m);
            sq[e] += __shfl_xor(sq[e], m);
        }
    }
    if (l15 == 0) {
        #pragma unroll
        for (int e = 0; e < 16; ++e) {
            int ch = (e >> 2) * 16 + quad * 4 + (e & 3);
            atomicAdd(&red_s[ch], s1[e]);
            atomicAdd(&red_q[ch], sq[e]);
        }
    }
    __syncthreads();
    float* dst = red0 + (size_t)(blockIdx.x & 3) * 128;
    if (t < 64)       atomicAdd(&dst[t], red_s[t]);
    else if (t < 128) atomicAdd(&dst[t], red_q[t - 64]);
}

// ---------------------------------------------------------------------------
// Gather-only pool with inlined BN0 finalize (scale/shift in LDS).
// ---------------------------------------------------------------------------
__global__ __launch_bounds__(256) void pool_max_kernel(
    const unsigned short* __restrict__ t_bf,
    const int* __restrict__ cnt, const int* __restrict__ bucket,
    const float* __restrict__ red0, const float* __restrict__ g0,
    const float* __restrict__ b0,
    unsigned short* __restrict__ down_bf, int M, int N)
{
    __shared__ float sc_s[64], sh_s[64];
    int t = threadIdx.x;
    if (t < 64) {
        float s = 0.f, q2 = 0.f;
        #pragma unroll
        for (int i = 0; i < 4; ++i) { s += red0[i * 128 + t]; q2 += red0[i * 128 + 64 + t]; }
        float m = s / (float)N;
        float var = q2 / (float)N - m * m;
        float sc = g0[t] / sqrtf(var + EPSF);
        sc_s[t] = sc;
        sh_s[t] = b0[t] - m * sc;
    }
    __syncthreads();

    int id = blockIdx.x * 256 + t;
    int s = id >> 4, cg = id & 15;
    if (s >= M) return;
    int n = cnt[s];
    const int4* bk4 = (const int4*)(bucket + (size_t)s * 16);
    float4 mx = make_float4(-INFINITY, -INFINITY, -INFINITY, -INFINITY);
    float4 mn = make_float4( INFINITY,  INFINITY,  INFINITY,  INFINITY);
    #pragma unroll
    for (int ch = 0; ch < 4; ++ch) {
        if (ch * 4 >= n) break;
        int4 b4 = bk4[ch];
        #pragma unroll
        for (int e = 0; e < 4; ++e) {
            int p = ch * 4 + e;
            if (p < n) {
                int idx = (e == 0) ? b4.x : (e == 1) ? b4.y : (e == 2) ? b4.z : b4.w;
                ushort4 v = *(const ushort4*)(t_bf + (size_t)idx * COUT + cg * 4);
                float f0 = bf2f(v.x), f1 = bf2f(v.y), f2 = bf2f(v.z), f3 = bf2f(v.w);
                mx.x = fmaxf(mx.x, f0); mn.x = fminf(mn.x, f0);
                mx.y = fmaxf(mx.y, f1); mn.y = fminf(mn.y, f1);
                mx.z = fmaxf(mx.z, f2); mn.z = fminf(mn.z, f2);
                mx.w = fmaxf(mx.w, f3); mn.w = fminf(mn.w, f3);
            }
        }
    }
    int c0 = cg * 4;
    float scx = sc_s[c0], scy = sc_s[c0 + 1], scz = sc_s[c0 + 2], scw = sc_s[c0 + 3];
    float shx = sh_s[c0], shy = sh_s[c0 + 1], shz = sh_s[c0 + 2], shw = sh_s[c0 + 3];
    ushort4 o;
    o.x = f2bf(eluf(scx * (scx >= 0.f ? mx.x : mn.x) + shx));
    o.y = f2bf(eluf(scy * (scy >= 0.f ? mx.y : mn.y) + shy));
    o.z = f2bf(eluf(scz * (scz >= 0.f ? mx.z : mn.z) + shz));
    o.w = f2bf(eluf(scw * (scw >= 0.f ? mx.w : mn.w) + shw));
    *(ushort4*)(down_bf + (size_t)s * COUT + c0) = o;
}

// o1t = bf16( ELU(scale1*o1 + shift1) ) with inlined BN finalize from red.
__global__ __launch_bounds__(256) void bn_elu_cvt_kernel(
    const float* __restrict__ o1, const float* __restrict__ red,
    const float* __restrict__ g, const float* __restrict__ bb,
    unsigned short* __restrict__ o1t, int n4, int M)
{
    __shared__ float sc_s[64], sh_s[64];
    int t = threadIdx.x;
    if (t < 64) {
        float m = red[t] / (float)M;
        float var = red[64 + t] / (float)M - m * m;
        float sc = g[t] / sqrtf(var + EPSF);
        sc_s[t] = sc;
        sh_s[t] = bb[t] - m * sc;
    }
    __syncthreads();
    int i = blockIdx.x * 256 + t;
    if (i < n4) {
        float4 v = ((const float4*)o1)[i];
        int c0 = (i & 15) * 4;
        ushort4 o;
        o.x = f2bf(eluf(v.x * sc_s[c0]     + sh_s[c0]));
        o.y = f2bf(eluf(v.y * sc_s[c0 + 1] + sh_s[c0 + 1]));
        o.z = f2bf(eluf(v.z * sc_s[c0 + 2] + sh_s[c0 + 2]));
        o.w = f2bf(eluf(v.w * sc_s[c0 + 3] + sh_s[c0 + 3]));
        ((ushort4*)o1t)[i] = o;
    }
}

// out = elu( elu(scale2*raw + shift2) + down ), inlined BN finalize.
__global__ __launch_bounds__(256) void final_kernel(
    float* __restrict__ out, const unsigned short* __restrict__ down_bf,
    const float* __restrict__ red, const float* __restrict__ g,
    const float* __restrict__ bb, int n4, int M)
{
    __shared__ float sc_s[64], sh_s[64];
    int t = threadIdx.x;
    if (t < 64) {
        float m = red[t] / (float)M;
        float var = red[64 + t] / (float)M - m * m;
        float sc = g[t] / sqrtf(var + EPSF);
        sc_s[t] = sc;
        sh_s[t] = bb[t] - m * sc;
    }
    __syncthreads();
    int i = blockIdx.x * 256 + t;
    if (i < n4) {
        float4 v = ((const float4*)out)[i];
        ushort4 d = ((const ushort4*)down_bf)[i];
        int c0 = (i & 15) * 4;
        v.x = eluf(eluf(v.x * sc_s[c0]     + sh_s[c0])     + bf2f(d.x));
        v.y = eluf(eluf(v.y * sc_s[c0 + 1] + sh_s[c0 + 1]) + bf2f(d.y));
        v.z = eluf(eluf(v.z * sc_s[c0 + 2] + sh_s[c0 + 2]) + bf2f(d.z));
        v.w = eluf(eluf(v.w * sc_s[c0 + 3] + sh_s[c0 + 3]) + bf2f(d.w));
        ((float4*)out)[i] = v;
    }
}

// ---------------------------------------------------------------------------
// MFMA implicit-GEMM sparse conv. v5: operand-swapped, LDS-free gather.
//   D = Wt_frag (A-op: channels x k) * gather_frag (B-op: k x points).
// Lane l15 loads 16B of ONE gathered row directly global->VGPR (B-operand
// needs col=l15, k=quad*8) -- no A staging, no barrier coupling. Zero row at
// in[M] makes every gather unconditional (precise counted vmcnt). Only W
// (8KB/k) is LDS double-buffered; raw s_barrier + manual lgkmcnt(0) lets
// gather loads stay in flight ACROSS barriers. Depth-2 gather prefetch via
// 3 named rotating register sets (27 = 9x3 exact unroll). D layout gives
// 16B contiguous fp32 stores (4 channels/point/lane).
// Block = 512 thr (8 waves x 2 point-tiles of 16) = 256 points.
// ---------------------------------------------------------------------------
__global__ __launch_bounds__(512, 4) void conv_mfma_kernel(
    const unsigned short* __restrict__ in,   // (M+1) x 64, row M = zeros
    const unsigned short* __restrict__ Wt,
    const int* __restrict__ nbrT, int M,
    float* __restrict__ out, float* __restrict__ red)
{
    __shared__ __align__(16) unsigned short W_lds[2][64 * 64];  // 16 KB
    __shared__ float red_sq[128];
    int t = threadIdx.x;

    // XCD-chunked bijective remap (m204)
    int nwg = gridDim.x;
    int q = nwg >> 3, r = nwg & 7;
    int xcd = blockIdx.x & 7, pos = blockIdx.x >> 3;
    int sb = (xcd < r ? xcd * (q + 1) : r * (q + 1) + (xcd - r) * q) + pos;
    int base = sb * 256;

    int w = t >> 6, lane = t & 63, l15 = lane & 15, quad = lane >> 4;

    // each wave owns 2 point-tiles of 16: points p0 (tile 2w), p1 (tile 2w+1)
    int p0 = base + 32 * w + l15;
    int p1 = p0 + 16;
    bool v0 = p0 < M, v1 = p1 < M;
    int pcl0 = v0 ? p0 : 0, pcl1 = v1 ? p1 : 0;

    // W staging: 512 threads x 16B = 8KB tile. wc = row (0..63), wq = slot.
    int wc = t >> 3, wq = t & 7, wcx = wc & 7;
    int wwo = wc * 64 + ((wq ^ wcx) * 8);

    float4v acc[2][4];
    #pragma unroll
    for (int s = 0; s < 2; ++s)
        #pragma unroll
        for (int n = 0; n < 4; ++n)
            acc[s][n] = (float4v){0.f, 0.f, 0.f, 0.f};

    // ---- prologue ----
    // idx for k=0..3 (fold validity into sign)
    int r00 = nbrT[pcl0],                int_r01 = 0;
    int r01 = nbrT[pcl1];
    int r10 = nbrT[(size_t)M + pcl0];
    int r11 = nbrT[(size_t)M + pcl1];
    int i20r = nbrT[(size_t)2 * M + pcl0];
    int i21r = nbrT[(size_t)2 * M + pcl1];
    int i30r = nbrT[(size_t)3 * M + pcl0];
    int i31r = nbrT[(size_t)3 * M + pcl1];
    (void)int_r01;
    int i20 = v0 ? i20r : -1, i21 = v1 ? i21r : -1;
    int i30 = v0 ? i30r : -1, i31 = v1 ? i31r : -1;

    // B-frag register sets: Sx = {tile0 kk0, tile0 kk32, tile1 kk0, tile1 kk32}
    short8 S0a, S0b, S0c, S0d, S1a, S1b, S1c, S1d, S2a, S2b, S2c, S2d;
    {   // issue k=0 into S0
        int e0 = (v0 && r00 >= 0) ? r00 : M;
        int e1 = (v1 && r01 >= 0) ? r01 : M;
        const short8* s0 = (const short8*)(in + (size_t)e0 * COUT);
        const short8* s1 = (const short8*)(in + (size_t)e1 * COUT);
        S0a = s0[quad]; S0b = s0[4 + quad]; S0c = s1[quad]; S0d = s1[4 + quad];
    }
    {   // issue k=1 into S1
        int e0 = (v0 && r10 >= 0) ? r10 : M;
        int e1 = (v1 && r11 >= 0) ? r11 : M;
        const short8* s0 = (const short8*)(in + (size_t)e0 * COUT);
        const short8* s1 = (const short8*)(in + (size_t)e1 * COUT);
        S1a = s0[quad]; S1b = s0[4 + quad]; S1c = s1[quad]; S1d = s1[4 + quad];
    }
    S2a = S0a; S2b = S0a; S2c = S0a; S2d = S0a;  // init (overwritten before use)

    unsigned short* Wc = W_lds[0];
    unsigned short* Wn = W_lds[1];
    {   // stage W(0)
        u16x8 w0 = *(const u16x8*)(Wt + wc * COUT + wq * 8);
        *(u16x8*)(Wc + wwo) = w0;
    }
    __syncthreads();

    auto ITER = [&](int k, short8& ua, short8& ub, short8& uc, short8& ud,
                           short8& xa, short8& xb, short8& xc, short8& xd) {
        // W frag for k+1 (clamped; slack = this compute phase, L2-hot)
        int kw = (k + 1 < KVOL) ? k + 1 : KVOL - 1;
        u16x8 wreg = *(const u16x8*)(Wt + (size_t)kw * (COUT * COUT) + wc * COUT + wq * 8);
        // issue gather for k+2 (clamped) into x-set; consumed 2 iters later
        {
            int e0 = (i20 >= 0) ? i20 : M;
            int e1 = (i21 >= 0) ? i21 : M;
            const short8* s0 = (const short8*)(in + (size_t)e0 * COUT);
            const short8* s1 = (const short8*)(in + (size_t)e1 * COUT);
            xa = s0[quad]; xb = s0[4 + quad]; xc = s1[quad]; xd = s1[4 + quad];
        }
        // idx chain: shift, load k+4 (clamped)
        i20 = i30; i21 = i31;
        int kn = (k + 4 < KVOL) ? k + 4 : KVOL - 1;
        int rr0 = nbrT[(size_t)kn * M + pcl0];
        int rr1 = nbrT[(size_t)kn * M + pcl1];
        i30 = v0 ? rr0 : -1;
        i31 = v1 ? rr1 : -1;

        // compute: 8 ds_read W-frags (A-op), 16 MFMA with u-set (B-op)
        __builtin_amdgcn_s_setprio(1);
        #pragma unroll
        for (int half = 0; half < 2; ++half) {
            int slb = quad + half * 4;
            short8 bt0 = half ? ub : ua;
            short8 bt1 = half ? ud : uc;
            #pragma unroll
            for (int n = 0; n < 4; ++n) {
                int rb = 16 * n + l15;
                short8 wf = *(const short8*)(Wc + rb * 64 + ((slb ^ (rb & 7)) * 8));
                acc[0][n] = __builtin_amdgcn_mfma_f32_16x16x32_bf16(wf, bt0, acc[0][n], 0, 0, 0);
                acc[1][n] = __builtin_amdgcn_mfma_f32_16x16x32_bf16(wf, bt1, acc[1][n], 0, 0, 0);
            }
        }
        __builtin_amdgcn_s_setprio(0);

        // stage W(k+1) into back buffer; raw barrier (NO vmcnt drain --
        // gather loads stay in flight across it)
        *(u16x8*)(Wn + wwo) = wreg;
        asm volatile("s_waitcnt lgkmcnt(0)" ::: "memory");
        __builtin_amdgcn_s_barrier();
        unsigned short* tmp = Wc; Wc = Wn; Wn = tmp;
    };

    for (int k = 0; k < KVOL; k += 3) {
        ITER(k,     S0a, S0b, S0c, S0d, S2a, S2b, S2c, S2d);
        ITER(k + 1, S1a, S1b, S1c, S1d, S0a, S0b, S0c, S0d);
        ITER(k + 2, S2a, S2b, S2c, S2d, S1a, S1b, S1c, S1d);
    }

    // stores: D row = channel (16n + quad*4 + e), col = point (l15).
    // Lane writes 4 consecutive channels of its point: one 16B fp32 store.
    #pragma unroll
    for (int s = 0; s < 2; ++s) {
        int p = (s == 0) ? p0 : p1;
        bool v = (s == 0) ? v0 : v1;
        if (v) {
            #pragma unroll
            for (int n = 0; n < 4; ++n) {
                float4 o;
                o.x = acc[s][n][0]; o.y = acc[s][n][1];
                o.z = acc[s][n][2]; o.w = acc[s][n][3];
                *(float4*)(out + (size_t)p * COUT + 16 * n + quad * 4) = o;
            }
        }
    }

    // fused BN stats: channel = 16n + quad*4 + e, reduce over points (l15)
    if (t < 128) red_sq[t] = 0.f;
    __syncthreads();
    #pragma unroll
    for (int n = 0; n < 4; ++n) {
        #pragma unroll
        for (int e = 0; e < 4; ++e) {
            float s1 = acc[0][n][e] + acc[1][n][e];
            float sq = acc[0][n][e] * acc[0][n][e] + acc[1][n][e] * acc[1][n][e];
            s1 += __shfl_xor(s1, 1); sq += __shfl_xor(sq, 1);
            s1 += __shfl_xor(s1, 2); sq += __shfl_xor(sq, 2);
            s1 += __shfl_xor(s1, 4); sq += __shfl_xor(sq, 4);
            s1 += __shfl_xor(s1, 8); sq += __shfl_xor(sq, 8);
            if (l15 == 0) {
                int ch = 16 * n + quad * 4 + e;
                atomicAdd(&red_sq[ch], s1);
                atomicAdd(&red_sq[64 + ch], sq);
            }
        }
    }
    __syncthreads();
    if (t < 128) atomicAdd(&red[t], red_sq[t]);
}

extern "C" void kernel_launch(void* const* d_in, const int* in_sizes, int n_in,
                              void* d_out, int out_size, void* d_ws, size_t ws_size,
                              hipStream_t stream)
{
    (void)n_in; (void)ws_size;
    const float* feats    = (const float*)d_in[0];
    const float* Wd       = (const float*)d_in[1];
    const float* g0       = (const float*)d_in[2];
    const float* b0       = (const float*)d_in[3];
    const float* W1       = (const float*)d_in[4];
    const float* g1       = (const float*)d_in[5];
    const float* b1       = (const float*)d_in[6];
    const float* W2       = (const float*)d_in[7];
    const float* g2       = (const float*)d_in[8];
    const float* b2       = (const float*)d_in[9];
    const int*   pool_seg = (const int*)d_in[10];
    const int*   conv_in  = (const int*)d_in[11];
    const int*   conv_out = (const int*)d_in[12];

    int N = in_sizes[0] / CIN;
    int M = out_size / COUT;
    int L = in_sizes[11] / KVOL;

    char* ws = (char*)d_ws;
    size_t off = 0;
    auto alloc = [&](size_t bytes) -> void* {
        void* p = ws + off;
        off = (off + bytes + 255) & ~(size_t)255;
        return p;
    };
    float*          o1      = (float*)alloc((size_t)M * COUT * 4);
    unsigned short* down_bf = (unsigned short*)alloc((size_t)(M + 1) * COUT * 2);
    unsigned short* o1t     = (unsigned short*)alloc((size_t)(M + 1) * COUT * 2);
    unsigned short* t_bf    = (unsigned short*)alloc((size_t)N * COUT * 2);
    int*            nbrT    = (int*)alloc((size_t)KVOL * M * 4);
    unsigned short* Wt1     = (unsigned short*)alloc((size_t)KVOL * COUT * COUT * 2);
    unsigned short* Wt2     = (unsigned short*)alloc((size_t)KVOL * COUT * COUT * 2);
    unsigned short* Wdt     = (unsigned short*)alloc((size_t)CIN * COUT * 2);
    int*            bucket  = (int*)alloc((size_t)M * 16 * 4);
    int*            cnt     = (int*)alloc((size_t)M * 4);         // cnt and red are
    float*          red     = (float*)alloc((size_t)768 * 4);     // adjacent: 1 memset
    float* red0 = red, *red1 = red + 512, *red2 = red + 640;

    hipMemsetAsync(nbrT, 0xFF, (size_t)KVOL * M * 4, stream);     // -1 = missing nbr
    hipMemsetAsync(cnt, 0, (size_t)((char*)(red + 768) - (char*)cnt), stream);
    hipMemsetAsync(down_bf + (size_t)M * COUT, 0, COUT * 2, stream);  // zero row M
    hipMemsetAsync(o1t + (size_t)M * COUT, 0, COUT * 2, stream);      // zero row M

    int nbB = (N + 255) / 256, nbL = (L + 255) / 256;
    prep_kernel<<<55 + nbB + nbL * KVOL, 256, 0, stream>>>(
        W1, W2, Wd, Wt1, Wt2, Wdt, pool_seg, cnt, bucket, N,
        conv_out, conv_in, nbrT, L, M, nbB, nbL);
    gemm_t_kernel<<<1024, 256, 0, stream>>>(feats, Wdt, N, t_bf, red0);
    pool_max_kernel<<<(M * 16 + 255) / 256, 256, 0, stream>>>(
        t_bf, cnt, bucket, red0, g0, b0, down_bf, M, N);

    int cblocks = (M + 255) / 256;
    int n4 = (M * COUT) / 4;
    conv_mfma_kernel<<<cblocks, 512, 0, stream>>>(down_bf, Wt1, nbrT, M, o1, red1);
    bn_elu_cvt_kernel<<<(n4 + 255) / 256, 256, 0, stream>>>(o1, red1, g1, b1, o1t, n4, M);
    conv_mfma_kernel<<<cblocks, 512, 0, stream>>>(o1t, Wt2, nbrT, M, (float*)d_out, red2);
    final_kernel<<<(n4 + 255) / 256, 256, 0, stream>>>(
        (float*)d_out, down_bf, red2, g2, b2, n4, M);
}